// Round 16
// baseline (49.213 us; speedup 1.0000x reference)
//
#include <hip/hip_runtime.h>

// Problem constants (match reference)
#define HH 256
#define WW 256
#define NB 2
#define NN 128
#define NSTEPS_K 50
#define NBLK 256                 // one block per CU -> co-residency guaranteed
#define MAGIC_G 0x11C0FFEE
#define MAGIC_E 0x22C0FFEE
#define MAGIC_R 0x33C0FFEE
#define MAGIC_X 0x5EC0DE00       // xcc publication tag (low byte = xcc id)
#define SPIN_G 400000
#define SPIN_E 120000
#define SPIN_R 120000

// ws float-offsets. ALL cross-block traffic via MALL-coherent relaxed atomics
// (R11: per-iteration acquire = invalidate storm; R12: per-block release =
// writeback storm). Flags reset in-kernel at end of every call.
#define WS_PART   0        // 256 floats  (per-block partials)
#define WS_GFLG   256      // 256 ints    (grad-done per block)
#define WS_RFLG   512      // 256 ints    (render-done per block)
#define WS_EREP   1024     // 16 slots * 64-int stride (evolve-done, 8 reps/batch)
#define WS_XCC    2048     // 2 ints      (evolve blocks' XCC id, tagged)
#define WS_FNODE  2112     // 256 u64 = 512 floats (final nodes)
#define WS_FIELD  4096     // quad field: NB*H*W cells * 32B (4MB), 32B-aligned
#define WS_NEEDED_BYTES ((WS_FIELD + (size_t)NB * HH * WW * 8) * 4)

static __device__ __forceinline__ int ld_i(int* p) {
    return __hip_atomic_load(p, __ATOMIC_RELAXED, __HIP_MEMORY_SCOPE_AGENT);
}
static __device__ __forceinline__ void st_i(int* p, int v) {
    __hip_atomic_store(p, v, __ATOMIC_RELAXED, __HIP_MEMORY_SCOPE_AGENT);
}
static __device__ __forceinline__ unsigned long long ld_u64(unsigned long long* p) {
    return __hip_atomic_load(p, __ATOMIC_RELAXED, __HIP_MEMORY_SCOPE_AGENT);
}
static __device__ __forceinline__ void st_u64(unsigned long long* p, unsigned long long v) {
    __hip_atomic_store(p, v, __ATOMIC_RELAXED, __HIP_MEMORY_SCOPE_AGENT);
}
static __device__ __forceinline__ float ld_f(float* p) {
    return __hip_atomic_load(p, __ATOMIC_RELAXED, __HIP_MEMORY_SCOPE_AGENT);
}
static __device__ __forceinline__ void st_f(float* p, float v) {
    __hip_atomic_store(p, v, __ATOMIC_RELAXED, __HIP_MEMORY_SCOPE_AGENT);
}
union F2U { float2 f2; unsigned long long u; };

static __device__ __forceinline__ int read_xcc() {
    int xr;
    asm volatile("s_getreg_b32 %0, hwreg(HW_REG_XCC_ID)" : "=s"(xr));
    return xr & 0xFF;
}

// jnp.gradient corner values, bit-exact clamped form (validated R2-R15).
static __device__ __forceinline__ float gy_at(const float* __restrict__ f, int i, int j) {
    int iu = max(i - 1, 0), id = min(i + 1, HH - 1);
    float s = (i == 0 || i == HH - 1) ? 1.0f : 0.5f;
    return s * (f[(id << 8) + j] - f[(iu << 8) + j]);
}
static __device__ __forceinline__ float gx_at(const float* __restrict__ f, int i, int j) {
    int jl = max(j - 1, 0), jr = min(j + 1, WW - 1);
    float s = (j == 0 || j == WW - 1) ? 1.0f : 0.5f;
    return s * (f[(i << 8) + jr] - f[(i << 8) + jl]);
}

__global__ __launch_bounds__(1024) void fused5_kernel(
        const float* __restrict__ pred,
        const float* __restrict__ nodes_in,
        float* __restrict__ ws,
        float* __restrict__ out) {
    float* partials = ws + WS_PART;
    int*   g_flags  = (int*)(ws + WS_GFLG);
    int*   r_flags  = (int*)(ws + WS_RFLG);
    int*   e_rep    = (int*)(ws + WS_EREP);
    int*   xcc_pub  = (int*)(ws + WS_XCC);
    unsigned long long* fnodes_u = (unsigned long long*)(ws + WS_FNODE);
    unsigned long long* field_u  = (unsigned long long*)(ws + WS_FIELD);
    const float4*       field_q  = (const float4*)(ws + WS_FIELD);

    const int blk = blockIdx.x;     // 0..255
    const int tid = threadIdx.x;    // 0..1023
    const int myBatch = blk >> 7;   // pixel batch this block renders

    // Evolve blocks publish their XCD id FIRST (helpers target its L2).
    if (blk < NB && tid == 0) st_i(&xcc_pub[blk], MAGIC_X | read_xcc());

    // ===== Phase 1: QUAD field via MALL atomics (512 cells/block, 32B/cell) ==
    // Cell (i,j) packs (gy,gx) of corners (i,j),(i,j1),(i1,j),(i1,j1) into one
    // 32B-aligned block -> ONE 64B line per bilerp sample (R6 layout, absmax
    // 0.0 validated). Redundant gradient math is free at 256-block parallelism.
    if (tid < 512) {
        int idx = blk * 512 + tid;          // 0 .. 131071
        int b = idx >> 16, p = idx & 0xFFFF;
        int i = p >> 8, j = p & (WW - 1);
        const float* f = pred + (b << 16);
        int i1 = min(i + 1, HH - 1);        // edge quads never sampled (clip 254.999)
        int j1 = min(j + 1, WW - 1);
        F2U u0, u1, u2, u3;
        u0.f2 = make_float2(gy_at(f, i, j),   gx_at(f, i, j));
        u1.f2 = make_float2(gy_at(f, i, j1),  gx_at(f, i, j1));
        u2.f2 = make_float2(gy_at(f, i1, j),  gx_at(f, i1, j));
        u3.f2 = make_float2(gy_at(f, i1, j1), gx_at(f, i1, j1));
        unsigned long long* cell = &field_u[(size_t)idx << 2];
        st_u64(&cell[0], u0.u);   // -> MALL, no dirty L2 lines
        st_u64(&cell[1], u1.u);
        st_u64(&cell[2], u2.u);
        st_u64(&cell[3], u3.u);
    }
    __syncthreads();                        // drains vmcnt pre-barrier
    if (tid == 0) st_i(&g_flags[blk], MAGIC_G);

    // ===== Phase 2a: sibling-XCD L2 warm (non-evolve blocks) ==================
    // 2MB/batch = 32768 lines; 32 siblings/XCD -> 1024 lines each, 1/thread.
    if (blk >= NB) {
        const int myxcc = read_xcc();
        __shared__ int s_pub[NB];
        if (tid == 0) {
            #pragma unroll
            for (int b = 0; b < NB; ++b) {
                int pub = 0;
                for (int it = 0; it < 50000; ++it) {   // set at kernel entry
                    pub = ld_i(&xcc_pub[b]);
                    if ((pub & (int)0xFFFFFF00) == MAGIC_X) break;
                    __builtin_amdgcn_s_sleep(1);
                }
                s_pub[b] = pub;
            }
        }
        __syncthreads();
        #pragma unroll
        for (int b = 0; b < NB; ++b) {
            int pub = s_pub[b];                       // block-uniform
            if ((pub & (int)0xFFFFFF00) == MAGIC_X && (pub & 0xFF) == myxcc) {
                const int rank = (blk >> 3) & 31;     // distinct among siblings
                if (tid == 0) {                       // 4 producer slabs gate my chunk
                    #pragma unroll
                    for (int k = 0; k < 4; ++k) {
                        int* fl = &g_flags[b * 128 + rank * 4 + k];
                        for (int it = 0; it < SPIN_G; ++it) {
                            if (ld_i(fl) == MAGIC_G) break;
                            __builtin_amdgcn_s_sleep(1);
                        }
                    }
                }
                __syncthreads();
                {   // warm 1024 lines (16B read of each 64B line)
                    int line = rank * 1024 + tid;     // 0..32767
                    float v = field_q[((size_t)b << 17) + ((size_t)line << 2)].x;
                    asm volatile("" :: "v"(v));
                }
            }
        }
    }

    // ===== Phase 2b: evolve (blocks 0..NB-1) ==================================
    if (blk < NB) {
        const int b = blk;
        const float4* gbq = field_q + ((size_t)b << 17);   // 2 float4 per cell

        if (tid < 64) {   // wave0 polls all 128 producer flags (2/lane)
            int f0 = b * 128 + tid * 2;
            for (int it = 0; it < SPIN_G; ++it) {
                bool ok = (ld_i(&g_flags[f0]) == MAGIC_G) &&
                          (ld_i(&g_flags[f0 + 1]) == MAGIC_G);
                if (__all(ok)) break;
                __builtin_amdgcn_s_sleep(1);
            }
        }
        __syncthreads();

        if (tid < 64) {
            const int l = tid;
            const int pl = (l + 63) & 63;
            const int nl = (l + 1) & 63;
            float4 nd = ((const float4*)nodes_in)[b * 64 + l];
            float y0n = nd.x, x0n = nd.y;      // node 2l
            float y1n = nd.z, x1n = nd.w;      // node 2l+1

            __builtin_amdgcn_s_setprio(1);
            for (int s = 0; s < NSTEPS_K; ++s) {
                // quad loads: 2 x dwordx4 per node, both in ONE 64B line
                float yca = fminf(fmaxf(y0n, 0.0f), 254.999f);
                float xca = fminf(fmaxf(x0n, 0.0f), 254.999f);
                int ra = (int)yca, ca = (int)xca;
                float wya = yca - (float)ra, wxa = xca - (float)ca;
                int basea = ((ra << 8) + ca) << 1;
                float4 qa0 = gbq[basea], qa1 = gbq[basea + 1];

                float ycb = fminf(fmaxf(y1n, 0.0f), 254.999f);
                float xcb = fminf(fmaxf(x1n, 0.0f), 254.999f);
                int rb = (int)ycb, cb = (int)xcb;
                float wyb = ycb - (float)rb, wxb = xcb - (float)cb;
                int baseb = ((rb << 8) + cb) << 1;
                float4 qb0 = gbq[baseb], qb1 = gbq[baseb + 1];

                // single shuffle round: neighbor positions
                float pya = __shfl(y0n, pl), pxa = __shfl(x0n, pl);
                float pyb = __shfl(y1n, pl), pxb = __shfl(x1n, pl);
                float nya = __shfl(y0n, nl), nxa = __shfl(x0n, nl);
                float nyb = __shfl(y1n, nl), nxb = __shfl(x1n, nl);

                // d2[i] = (x[i+1] + x[i-1]) - 2 x[i]
                float d2ya = (y1n + pyb) - 2.0f * y0n;
                float d2xa = (x1n + pxb) - 2.0f * x0n;
                float d2yb = (nya + y0n) - 2.0f * y1n;
                float d2xb = (nxa + x0n) - 2.0f * x1n;
                float d2pyb = (y0n + pya) - 2.0f * pyb;
                float d2pxb = (x0n + pxa) - 2.0f * pxb;
                float d2nya = (nyb + y1n) - 2.0f * nya;
                float d2nxa = (nxb + x1n) - 2.0f * nxa;

                // d4[i] = (d2[i+1] + d2[i-1]) - 2 d2[i]
                float d4ya = (d2yb + d2pyb) - 2.0f * d2ya;
                float d4xa = (d2xb + d2pxb) - 2.0f * d2xa;
                float d4yb = (d2nya + d2ya) - 2.0f * d2yb;
                float d4xb = (d2nxa + d2xa) - 2.0f * d2xb;

                // bilerp (reference term order; quad comps = a00,a01 | a10,a11)
                float ua = 1.0f - wya, va = 1.0f - wxa;
                float bya = qa0.x * ua * va + qa0.z * ua * wxa + qa1.x * wya * va + qa1.z * wya * wxa;
                float bxa = qa0.y * ua * va + qa0.w * ua * wxa + qa1.y * wya * va + qa1.w * wya * wxa;
                float ub = 1.0f - wyb, vb = 1.0f - wxb;
                float byb = qb0.x * ub * vb + qb0.z * ub * wxb + qb1.x * wyb * vb + qb1.z * wyb * wxb;
                float bxb = qb0.y * ub * vb + qb0.w * ub * wxb + qb1.y * wyb * vb + qb1.w * wyb * wxb;

                // x += STEPSZ*(ALPHA*d2 - BETA*d4 + ext); clip [0,255]
                y0n = y0n + 0.1f * ((0.01f * d2ya - 0.01f * d4ya) + (-10.0f * bya));
                x0n = x0n + 0.1f * ((0.01f * d2xa - 0.01f * d4xa) + (-10.0f * bxa));
                y1n = y1n + 0.1f * ((0.01f * d2yb - 0.01f * d4yb) + (-10.0f * byb));
                x1n = x1n + 0.1f * ((0.01f * d2xb - 0.01f * d4xb) + (-10.0f * bxb));
                y0n = fminf(fmaxf(y0n, 0.0f), 255.0f);
                x0n = fminf(fmaxf(x0n, 0.0f), 255.0f);
                y1n = fminf(fmaxf(y1n, 0.0f), 255.0f);
                x1n = fminf(fmaxf(x1n, 0.0f), 255.0f);
            }
            __builtin_amdgcn_s_setprio(0);

            // publish nodes via MALL atomics; vmcnt(0) orders flag AFTER data
            F2U c0, c1;
            c0.f2 = make_float2(y0n, x0n);
            c1.f2 = make_float2(y1n, x1n);
            st_u64(&fnodes_u[b * 128 + 2 * l], c0.u);
            st_u64(&fnodes_u[b * 128 + 2 * l + 1], c1.u);
            asm volatile("s_waitcnt vmcnt(0)" ::: "memory");
            if (l == 0) {
                #pragma unroll
                for (int k = 0; k < 8; ++k) st_i(&e_rep[(b * 8 + k) * 64], MAGIC_E);
            }
        }
        __syncthreads();
    }

    // ===== e-wait: only myBatch's flag, replicated lines ======================
    if (tid == 0) {
        int* rep = &e_rep[(myBatch * 8 + (blk & 7)) * 64];
        for (int it = 0; it < SPIN_E; ++it) {
            if (ld_i(rep) == MAGIC_E) break;
            __builtin_amdgcn_s_sleep(8);
        }
    }
    __syncthreads();

    // ===== Phase 3: render (512 px/block, batch = myBatch) ====================
    __shared__ float nny[NN], nnx[NN];
    __shared__ float p0y[NN], p0x[NN], sdy[NN], sdx[NN], sidd[NN];
    if (tid < NN) {   // stage nodes via MALL atomic loads
        F2U cv; cv.u = ld_u64(&fnodes_u[myBatch * 128 + tid]);
        nny[tid] = cv.f2.x; nnx[tid] = cv.f2.y;
    }
    __syncthreads();
    if (tid < NN) {
        float ay = nny[tid], ax = nnx[tid];
        int j = (tid + 1) & (NN - 1);
        float cy = nny[j], cx = nnx[j];
        float ddy = cy - ay, ddx = cx - ax;
        p0y[tid] = ay; p0x[tid] = ax;
        sdy[tid] = ddy; sdx[tid] = ddx;
        sidd[tid] = 1.0f / (ddy * ddy + ddx * ddx + 1e-8f);
    }
    __syncthreads();

    float se = 0.0f;
    if (tid < 512) {
        int pixin = (blk & 127) * 512 + tid;    // 0 .. 65535 within batch
        float qy = (float)(pixin >> 8);
        float qx = (float)(pixin & (WW - 1));
        float minr2 = 1e30f;
        #pragma unroll 8
        for (int s = 0; s < NN; ++s) {
            float qpy = qy - p0y[s];
            float qpx = qx - p0x[s];
            float t = (qpy * sdy[s] + qpx * sdx[s]) * sidd[s];
            t = fminf(fmaxf(t, 0.0f), 1.0f);
            float ry = qpy - t * sdy[s];
            float rx = qpx - t * sdx[s];
            minr2 = fminf(minr2, ry * ry + rx * rx);
        }
        float dist = fminf(sqrtf(minr2 + 1e-12f), 15.0f);
        float e = pred[(myBatch << 16) + pixin] - dist;
        se = e * e;
    }
    for (int off = 32; off > 0; off >>= 1) se += __shfl_down(se, off);
    __shared__ float red[16];
    if ((tid & 63) == 0) red[tid >> 6] = se;   // waves 8..15 write 0
    __syncthreads();
    if (tid == 0) {
        float p = 0.0f;
        #pragma unroll
        for (int w = 0; w < 8; ++w) p += red[w];
        st_f(&partials[blk], p);
        asm volatile("s_waitcnt vmcnt(0)" ::: "memory");   // partial before flag
        st_i(&r_flags[blk], MAGIC_R);
    }

    // ===== Phase 4: finalize + flag reset (block 0) ===========================
    if (blk == 0 && tid < 64) {
        for (int it = 0; it < SPIN_R; ++it) {
            bool ok = (ld_i(&r_flags[tid*4+0]) == MAGIC_R) &&
                      (ld_i(&r_flags[tid*4+1]) == MAGIC_R) &&
                      (ld_i(&r_flags[tid*4+2]) == MAGIC_R) &&
                      (ld_i(&r_flags[tid*4+3]) == MAGIC_R);
            if (__all(ok)) break;
            __builtin_amdgcn_s_sleep(8);
        }
        float s = 0.0f;
        #pragma unroll
        for (int k = 0; k < 4; ++k)   // fixed order -> deterministic
            s += ld_f(&partials[tid + (k << 6)]);
        for (int off = 32; off > 0; off >>= 1) s += __shfl_down(s, off);
        if (tid == 0) out[0] = s * (1.0f / (float)(NB * HH * WW));
        // reset flags (relaxed MALL stores; everyone is past their last read)
        #pragma unroll
        for (int k = 0; k < 4; ++k) { st_i(&g_flags[tid*4+k], 0); st_i(&r_flags[tid*4+k], 0); }
        if (tid < 16) st_i(&e_rep[tid * 64], 0);
        if (tid < NB) st_i(&xcc_pub[tid], 0);
    }
}

// ---------------- fallback (ws too small): 2-kernel path ---------------------
__device__ __forceinline__ void sample_grad_direct(const float* __restrict__ f,
                                                   float y, float x,
                                                   float& by, float& bx) {
    float yc = fminf(fmaxf(y, 0.0f), 254.999f);
    float xc = fminf(fmaxf(x, 0.0f), 254.999f);
    int r0 = (int)yc, c0 = (int)xc;
    int r1 = r0 + 1, c1 = c0 + 1;
    float wy = yc - (float)r0, wx = xc - (float)c0;
    int rm = max(r0 - 1, 0), rp = min(r1 + 1, HH - 1);
    int cm = max(c0 - 1, 0), cp = min(c1 + 1, WW - 1);
    float sy0 = (r0 == 0) ? 1.0f : 0.5f;
    float sy1 = (r1 == HH - 1) ? 1.0f : 0.5f;
    float sx0 = (c0 == 0) ? 1.0f : 0.5f;
    float sx1 = (c1 == WW - 1) ? 1.0f : 0.5f;
    const float* fr0 = f + (r0 << 8);
    const float* fr1 = f + (r1 << 8);
    const float* frm = f + (rm << 8);
    const float* frp = f + (rp << 8);
    float f00 = fr0[c0], f01 = fr0[c1];
    float f10 = fr1[c0], f11 = fr1[c1];
    float f0m = fr0[cm], f0p = fr0[cp];
    float f1m = fr1[cm], f1p = fr1[cp];
    float fm0 = frm[c0], fm1 = frm[c1];
    float fp0 = frp[c0], fp1 = frp[c1];
    float gy00 = sy0 * (f10 - fm0), gy01 = sy0 * (f11 - fm1);
    float gy10 = sy1 * (fp0 - f00), gy11 = sy1 * (fp1 - f01);
    float gx00 = sx0 * (f01 - f0m), gx01 = sx1 * (f0p - f00);
    float gx10 = sx0 * (f11 - f1m), gx11 = sx1 * (f1p - f10);
    float u = 1.0f - wy, v = 1.0f - wx;
    by = gy00 * u * v + gy01 * u * wx + gy10 * wy * v + gy11 * wy * wx;
    bx = gx00 * u * v + gx01 * u * wx + gx10 * wy * v + gx11 * wy * wx;
}

__global__ __launch_bounds__(64, 1) void evolve_direct_kernel(
        const float* __restrict__ pred,
        const float* __restrict__ nodes_in,
        float* __restrict__ nodes_out,
        int* __restrict__ counter) {
    const int b = blockIdx.x;
    const int l = threadIdx.x;
    if (b == 0 && l == 0)
        __hip_atomic_store(counter, 0, __ATOMIC_RELAXED, __HIP_MEMORY_SCOPE_AGENT);
    const float* f = pred + b * HH * WW;
    const int pl = (l + 63) & 63;
    const int nl = (l + 1) & 63;
    float4 nd = ((const float4*)nodes_in)[b * 64 + l];
    float y0n = nd.x, x0n = nd.y, y1n = nd.z, x1n = nd.w;
    for (int s = 0; s < NSTEPS_K; ++s) {
        float by0, bx0, by1, bx1;
        sample_grad_direct(f, y0n, x0n, by0, bx0);
        sample_grad_direct(f, y1n, x1n, by1, bx1);
        float pya = __shfl(y0n, pl), pxa = __shfl(x0n, pl);
        float pyb = __shfl(y1n, pl), pxb = __shfl(x1n, pl);
        float nya = __shfl(y0n, nl), nxa = __shfl(x0n, nl);
        float nyb = __shfl(y1n, nl), nxb = __shfl(x1n, nl);
        float d2ya = (y1n + pyb) - 2.0f * y0n;
        float d2xa = (x1n + pxb) - 2.0f * x0n;
        float d2yb = (nya + y0n) - 2.0f * y1n;
        float d2xb = (nxa + x0n) - 2.0f * x1n;
        float d2pyb = (y0n + pya) - 2.0f * pyb;
        float d2pxb = (x0n + pxa) - 2.0f * pxb;
        float d2nya = (nyb + y1n) - 2.0f * nya;
        float d2nxa = (nxb + x1n) - 2.0f * nxa;
        float d4ya = (d2yb + d2pyb) - 2.0f * d2ya;
        float d4xa = (d2xb + d2pxb) - 2.0f * d2xa;
        float d4yb = (d2nya + d2ya) - 2.0f * d2yb;
        float d4xb = (d2nxa + d2xa) - 2.0f * d2xb;
        y0n = y0n + 0.1f * ((0.01f * d2ya - 0.01f * d4ya) + (-10.0f * by0));
        x0n = x0n + 0.1f * ((0.01f * d2xa - 0.01f * d4xa) + (-10.0f * bx0));
        y1n = y1n + 0.1f * ((0.01f * d2yb - 0.01f * d4yb) + (-10.0f * by1));
        x1n = x1n + 0.1f * ((0.01f * d2xb - 0.01f * d4xb) + (-10.0f * bx1));
        y0n = fminf(fmaxf(y0n, 0.0f), 255.0f);
        x0n = fminf(fmaxf(x0n, 0.0f), 255.0f);
        y1n = fminf(fmaxf(y1n, 0.0f), 255.0f);
        x1n = fminf(fmaxf(x1n, 0.0f), 255.0f);
    }
    float4 o4; o4.x = y0n; o4.y = x0n; o4.z = y1n; o4.w = x1n;
    ((float4*)nodes_out)[b * 64 + l] = o4;
}

#define RBLK ((HH * WW) / 256)
#define NPART (NB * RBLK)

__global__ void render_kernel(const float* __restrict__ pred,
                              const float* __restrict__ nodes,
                              float* __restrict__ partials,
                              int* __restrict__ counter,
                              float* __restrict__ out) {
    const int b = blockIdx.y;
    const int chunk = blockIdx.x;
    const int tid = threadIdx.x;
    __shared__ float p0y[NN], p0x[NN], sdy[NN], sdx[NN], sidd[NN];
    if (tid < NN) {
        float ay = nodes[(b * NN + tid) * 2 + 0];
        float ax = nodes[(b * NN + tid) * 2 + 1];
        int j = (tid + 1) & (NN - 1);
        float cy = nodes[(b * NN + j) * 2 + 0];
        float cx = nodes[(b * NN + j) * 2 + 1];
        float ddy = cy - ay, ddx = cx - ax;
        p0y[tid] = ay; p0x[tid] = ax;
        sdy[tid] = ddy; sdx[tid] = ddx;
        sidd[tid] = 1.0f / (ddy * ddy + ddx * ddx + 1e-8f);
    }
    __syncthreads();
    const int pix = chunk * 256 + tid;
    const float qy = (float)(pix >> 8);
    const float qx = (float)(pix & (WW - 1));
    float minr2 = 1e30f;
#pragma unroll 8
    for (int s = 0; s < NN; ++s) {
        float qpy = qy - p0y[s];
        float qpx = qx - p0x[s];
        float t = (qpy * sdy[s] + qpx * sdx[s]) * sidd[s];
        t = fminf(fmaxf(t, 0.0f), 1.0f);
        float ry = qpy - t * sdy[s];
        float rx = qpx - t * sdx[s];
        minr2 = fminf(minr2, ry * ry + rx * rx);
    }
    float dist = fminf(sqrtf(minr2 + 1e-12f), 15.0f);
    float e = pred[b * HH * WW + pix] - dist;
    float se = e * e;
    for (int off = 32; off > 0; off >>= 1) se += __shfl_down(se, off);
    __shared__ float red[4];
    if ((tid & 63) == 0) red[tid >> 6] = se;
    __syncthreads();
    __shared__ int lastBlk;
    if (tid == 0) {
        float p = (red[0] + red[1]) + (red[2] + red[3]);
        __hip_atomic_store(&partials[b * RBLK + chunk], p, __ATOMIC_RELEASE, __HIP_MEMORY_SCOPE_AGENT);
        int t = __hip_atomic_fetch_add(counter, 1, __ATOMIC_ACQ_REL, __HIP_MEMORY_SCOPE_AGENT);
        lastBlk = (t == NPART - 1);
    }
    __syncthreads();
    if (lastBlk) {
        float v = __hip_atomic_load(&partials[tid], __ATOMIC_RELAXED, __HIP_MEMORY_SCOPE_AGENT)
                + __hip_atomic_load(&partials[tid + 256], __ATOMIC_RELAXED, __HIP_MEMORY_SCOPE_AGENT);
        for (int off = 32; off > 0; off >>= 1) v += __shfl_down(v, off);
        __shared__ float red2[4];
        if ((tid & 63) == 0) red2[tid >> 6] = v;
        __syncthreads();
        if (tid == 0)
            out[0] = ((red2[0] + red2[1]) + (red2[2] + red2[3])) * (1.0f / (float)(NB * HH * WW));
    }
}

extern "C" void kernel_launch(void* const* d_in, const int* in_sizes, int n_in,
                              void* d_out, int out_size, void* d_ws, size_t ws_size,
                              hipStream_t stream) {
    const float* pred = (const float*)d_in[0];    // (B,1,H,W) f32
    const float* nodes = (const float*)d_in[1];   // (B,N,2) f32
    float* ws = (float*)d_ws;

    if (ws_size >= WS_NEEDED_BYTES) {
        fused5_kernel<<<dim3(NBLK), dim3(1024), 0, stream>>>(pred, nodes, ws, (float*)d_out);
    } else {
        float* partials = ws;                  // 512 f
        float* fnodes = ws + 512;              // 512 f
        int* counter = (int*)(ws + 1024);
        evolve_direct_kernel<<<dim3(NB), dim3(64), 0, stream>>>(pred, nodes, fnodes, counter);
        render_kernel<<<dim3(RBLK, NB), dim3(256), 0, stream>>>(pred, fnodes, partials,
                                                                counter, (float*)d_out);
    }
}

// Round 17
// 43.842 us; speedup vs baseline: 1.1225x; 1.1225x over previous
//
#include <hip/hip_runtime.h>

// Problem constants (match reference)
#define HH 256
#define WW 256
#define NB 2
#define NN 128
#define NSTEPS_K 50
#define NBLK 256                 // one block per CU -> co-residency guaranteed
#define MAGIC_G 0x11C0FFEE
#define MAGIC_E 0x22C0FFEE
#define MAGIC_R 0x33C0FFEE
#define MAGIC_X 0x5EC0DE00       // xcc publication tag (low byte = xcc id)
#define SPIN_G 400000
#define SPIN_E 120000
#define SPIN_R 120000

// ws float-offsets. ALL cross-block traffic via MALL-coherent relaxed atomics
// (R11: per-iteration acquire = invalidate storm; R12: per-block release =
// writeback storm; R16: 8B-atomic quad writes = 16MB RMW blowup -> float2 only).
#define WS_PART   0        // 256 floats  (per-block partials)
#define WS_GFLG   256      // 256 ints    (grad-done per block)
#define WS_RFLG   512      // 256 ints    (render-done per block)
#define WS_EREP   1024     // 16 slots * 64-int stride (evolve-done, 8 reps/batch)
#define WS_XCC    2048     // 2 ints      (evolve blocks' XCC id, tagged)
#define WS_FNODE  2112     // 256 u64 = 512 floats (final nodes)
#define WS_FIELD  4096     // NB*H*W float2 (1MB), 8B-aligned
#define WS_NEEDED_BYTES ((WS_FIELD + (size_t)NB * HH * WW * 2) * 4)

static __device__ __forceinline__ int ld_i(int* p) {
    return __hip_atomic_load(p, __ATOMIC_RELAXED, __HIP_MEMORY_SCOPE_AGENT);
}
static __device__ __forceinline__ void st_i(int* p, int v) {
    __hip_atomic_store(p, v, __ATOMIC_RELAXED, __HIP_MEMORY_SCOPE_AGENT);
}
static __device__ __forceinline__ unsigned long long ld_u64(unsigned long long* p) {
    return __hip_atomic_load(p, __ATOMIC_RELAXED, __HIP_MEMORY_SCOPE_AGENT);
}
static __device__ __forceinline__ void st_u64(unsigned long long* p, unsigned long long v) {
    __hip_atomic_store(p, v, __ATOMIC_RELAXED, __HIP_MEMORY_SCOPE_AGENT);
}
static __device__ __forceinline__ float ld_f(float* p) {
    return __hip_atomic_load(p, __ATOMIC_RELAXED, __HIP_MEMORY_SCOPE_AGENT);
}
static __device__ __forceinline__ void st_f(float* p, float v) {
    __hip_atomic_store(p, v, __ATOMIC_RELAXED, __HIP_MEMORY_SCOPE_AGENT);
}
union F2U { float2 f2; unsigned long long u; };

// 16B row-pair load at 8B alignment -> one global_load_dwordx4.
// r[0]=cell0.gy r[1]=cell0.gx r[2]=cell1.gy r[3]=cell1.gx (bit-identical use).
typedef float f4v __attribute__((ext_vector_type(4)));
static __device__ __forceinline__ f4v ld_pair(const float2* p) {
    f4v r;
    __builtin_memcpy(&r, p, sizeof(f4v));
    return r;
}

static __device__ __forceinline__ int read_xcc() {
    int xr;
    asm volatile("s_getreg_b32 %0, hwreg(HW_REG_XCC_ID)" : "=s"(xr));
    return xr & 0xFF;
}

__global__ __launch_bounds__(1024) void fused4_kernel(
        const float* __restrict__ pred,
        const float* __restrict__ nodes_in,
        float* __restrict__ ws,
        float* __restrict__ out) {
    float* partials = ws + WS_PART;
    int*   g_flags  = (int*)(ws + WS_GFLG);
    int*   r_flags  = (int*)(ws + WS_RFLG);
    int*   e_rep    = (int*)(ws + WS_EREP);
    int*   xcc_pub  = (int*)(ws + WS_XCC);
    unsigned long long* fnodes_u = (unsigned long long*)(ws + WS_FNODE);
    unsigned long long* field_u  = (unsigned long long*)(ws + WS_FIELD);
    const float2*       field_f2 = (const float2*)(ws + WS_FIELD);

    const int blk = blockIdx.x;     // 0..255
    const int tid = threadIdx.x;    // 0..1023
    const int myBatch = blk >> 7;   // pixel batch this block renders

    // Evolve blocks publish their XCD id FIRST (helpers target its L2).
    if (blk < NB && tid == 0) st_i(&xcc_pub[blk], MAGIC_X | read_xcc());

    // ========== Phase 1: gradient field via MALL atomics (512 cells/block) ===
    if (tid < 512) {
        int idx = blk * 512 + tid;          // 0 .. 131071
        int b = idx >> 16, p = idx & 0xFFFF;
        int i = p >> 8, j = p & (WW - 1);
        const float* f = pred + (b << 16);
        int iu = max(i - 1, 0), id = min(i + 1, HH - 1);
        int jl = max(j - 1, 0), jr = min(j + 1, WW - 1);
        float sy = (i == 0 || i == HH - 1) ? 1.0f : 0.5f;
        float sx = (j == 0 || j == WW - 1) ? 1.0f : 0.5f;
        F2U cv;
        cv.f2 = make_float2(sy * (f[(id << 8) + j] - f[(iu << 8) + j]),
                            sx * (f[(i << 8) + jr] - f[(i << 8) + jl]));
        st_u64(&field_u[idx], cv.u);        // -> MALL, no dirty L2 line
    }
    __syncthreads();                        // drains vmcnt pre-barrier
    if (tid == 0) st_i(&g_flags[blk], MAGIC_G);

    // ========== Phase 2a: sibling-XCD L2 warm (non-evolve blocks) =============
    if (blk >= NB) {
        const int myxcc = read_xcc();
        __shared__ int s_pub[NB];
        if (tid == 0) {
            #pragma unroll
            for (int b = 0; b < NB; ++b) {
                int pub = 0;
                for (int it = 0; it < 50000; ++it) {   // set at kernel entry
                    pub = ld_i(&xcc_pub[b]);
                    if ((pub & (int)0xFFFFFF00) == MAGIC_X) break;
                    __builtin_amdgcn_s_sleep(1);
                }
                s_pub[b] = pub;
            }
        }
        __syncthreads();
        #pragma unroll
        for (int b = 0; b < NB; ++b) {
            int pub = s_pub[b];                       // block-uniform
            if ((pub & (int)0xFFFFFF00) == MAGIC_X && (pub & 0xFF) == myxcc) {
                const int rank = (blk >> 3) & 31;     // distinct among siblings
                if (tid == 0) {                       // 4 producer slabs gate my chunk
                    #pragma unroll
                    for (int k = 0; k < 4; ++k) {
                        int* fl = &g_flags[b * 128 + rank * 4 + k];
                        for (int it = 0; it < SPIN_G; ++it) {
                            if (ld_i(fl) == MAGIC_G) break;
                            __builtin_amdgcn_s_sleep(1);
                        }
                    }
                }
                __syncthreads();
                if (tid < 256) {                      // warm 256 lines (8B/line)
                    int line = rank * 256 + tid;
                    float v = field_f2[(b << 16) + (line << 3)].x;
                    asm volatile("" :: "v"(v));
                }
            }
        }
    }

    // ========== Phase 2b: evolve (blocks 0..NB-1) =============================
    if (blk < NB) {
        const int b = blk;
        const float2* gb = field_f2 + (b << 16);

        if (tid < 64) {   // wave0 polls all 128 producer flags (2/lane)
            int f0 = b * 128 + tid * 2;
            for (int it = 0; it < SPIN_G; ++it) {
                bool ok = (ld_i(&g_flags[f0]) == MAGIC_G) &&
                          (ld_i(&g_flags[f0 + 1]) == MAGIC_G);
                if (__all(ok)) break;
                __builtin_amdgcn_s_sleep(1);
            }
        }
        __syncthreads();

        if (tid < 64) {
            const int l = tid;
            const int pl = (l + 63) & 63;
            const int nl = (l + 1) & 63;
            float4 nd = ((const float4*)nodes_in)[b * 64 + l];
            float y0n = nd.x, x0n = nd.y;      // node 2l
            float y1n = nd.z, x1n = nd.w;      // node 2l+1

            __builtin_amdgcn_s_setprio(1);
            for (int s = 0; s < NSTEPS_K; ++s) {
                // 4 x dwordx4 row-pair loads (sibling-warmed L2 hits)
                float yca = fminf(fmaxf(y0n, 0.0f), 254.999f);
                float xca = fminf(fmaxf(x0n, 0.0f), 254.999f);
                int ra = (int)yca, ca = (int)xca;
                float wya = yca - (float)ra, wxa = xca - (float)ca;
                int basea = (ra << 8) + ca;
                f4v ra0 = ld_pair(&gb[basea]);        // a00.gy a00.gx a01.gy a01.gx
                f4v ra1 = ld_pair(&gb[basea + WW]);   // a10.gy a10.gx a11.gy a11.gx

                float ycb = fminf(fmaxf(y1n, 0.0f), 254.999f);
                float xcb = fminf(fmaxf(x1n, 0.0f), 254.999f);
                int rb = (int)ycb, cb = (int)xcb;
                float wyb = ycb - (float)rb, wxb = xcb - (float)cb;
                int baseb = (rb << 8) + cb;
                f4v rb0 = ld_pair(&gb[baseb]);
                f4v rb1 = ld_pair(&gb[baseb + WW]);

                // single shuffle round: neighbor positions
                float pya = __shfl(y0n, pl), pxa = __shfl(x0n, pl);
                float pyb = __shfl(y1n, pl), pxb = __shfl(x1n, pl);
                float nya = __shfl(y0n, nl), nxa = __shfl(x0n, nl);
                float nyb = __shfl(y1n, nl), nxb = __shfl(x1n, nl);

                // d2[i] = (x[i+1] + x[i-1]) - 2 x[i]
                float d2ya = (y1n + pyb) - 2.0f * y0n;
                float d2xa = (x1n + pxb) - 2.0f * x0n;
                float d2yb = (nya + y0n) - 2.0f * y1n;
                float d2xb = (nxa + x0n) - 2.0f * x1n;
                float d2pyb = (y0n + pya) - 2.0f * pyb;
                float d2pxb = (x0n + pxa) - 2.0f * pxb;
                float d2nya = (nyb + y1n) - 2.0f * nya;
                float d2nxa = (nxb + x1n) - 2.0f * nxa;

                // d4[i] = (d2[i+1] + d2[i-1]) - 2 d2[i]
                float d4ya = (d2yb + d2pyb) - 2.0f * d2ya;
                float d4xa = (d2xb + d2pxb) - 2.0f * d2xa;
                float d4yb = (d2nya + d2ya) - 2.0f * d2yb;
                float d4xb = (d2nxa + d2xa) - 2.0f * d2xb;

                // bilerp (reference term order; component mapping unchanged)
                float ua = 1.0f - wya, va = 1.0f - wxa;
                float bya = ra0[0] * ua * va + ra0[2] * ua * wxa + ra1[0] * wya * va + ra1[2] * wya * wxa;
                float bxa = ra0[1] * ua * va + ra0[3] * ua * wxa + ra1[1] * wya * va + ra1[3] * wya * wxa;
                float ub = 1.0f - wyb, vb = 1.0f - wxb;
                float byb = rb0[0] * ub * vb + rb0[2] * ub * wxb + rb1[0] * wyb * vb + rb1[2] * wyb * wxb;
                float bxb = rb0[1] * ub * vb + rb0[3] * ub * wxb + rb1[1] * wyb * vb + rb1[3] * wyb * wxb;

                // x += STEPSZ*(ALPHA*d2 - BETA*d4 + ext); clip [0,255]
                y0n = y0n + 0.1f * ((0.01f * d2ya - 0.01f * d4ya) + (-10.0f * bya));
                x0n = x0n + 0.1f * ((0.01f * d2xa - 0.01f * d4xa) + (-10.0f * bxa));
                y1n = y1n + 0.1f * ((0.01f * d2yb - 0.01f * d4yb) + (-10.0f * byb));
                x1n = x1n + 0.1f * ((0.01f * d2xb - 0.01f * d4xb) + (-10.0f * bxb));
                y0n = fminf(fmaxf(y0n, 0.0f), 255.0f);
                x0n = fminf(fmaxf(x0n, 0.0f), 255.0f);
                y1n = fminf(fmaxf(y1n, 0.0f), 255.0f);
                x1n = fminf(fmaxf(x1n, 0.0f), 255.0f);
            }
            __builtin_amdgcn_s_setprio(0);

            // publish nodes via MALL atomics; vmcnt(0) orders flag AFTER data
            F2U c0, c1;
            c0.f2 = make_float2(y0n, x0n);
            c1.f2 = make_float2(y1n, x1n);
            st_u64(&fnodes_u[b * 128 + 2 * l], c0.u);
            st_u64(&fnodes_u[b * 128 + 2 * l + 1], c1.u);
            asm volatile("s_waitcnt vmcnt(0)" ::: "memory");
            if (l == 0) {
                #pragma unroll
                for (int k = 0; k < 8; ++k) st_i(&e_rep[(b * 8 + k) * 64], MAGIC_E);
            }
        }
        __syncthreads();
    }

    // ========== e-wait: only myBatch's flag, replicated lines =================
    if (tid == 0) {
        int* rep = &e_rep[(myBatch * 8 + (blk & 7)) * 64];
        for (int it = 0; it < SPIN_E; ++it) {
            if (ld_i(rep) == MAGIC_E) break;
            __builtin_amdgcn_s_sleep(8);
        }
    }
    __syncthreads();

    // ========== Phase 3: render (512 px/block, batch = myBatch) ===============
    __shared__ float nny[NN], nnx[NN];
    __shared__ float p0y[NN], p0x[NN], sdy[NN], sdx[NN], sidd[NN];
    if (tid < NN) {   // stage nodes via MALL atomic loads
        F2U cv; cv.u = ld_u64(&fnodes_u[myBatch * 128 + tid]);
        nny[tid] = cv.f2.x; nnx[tid] = cv.f2.y;
    }
    __syncthreads();
    if (tid < NN) {
        float ay = nny[tid], ax = nnx[tid];
        int j = (tid + 1) & (NN - 1);
        float cy = nny[j], cx = nnx[j];
        float ddy = cy - ay, ddx = cx - ax;
        p0y[tid] = ay; p0x[tid] = ax;
        sdy[tid] = ddy; sdx[tid] = ddx;
        sidd[tid] = 1.0f / (ddy * ddy + ddx * ddx + 1e-8f);
    }
    __syncthreads();

    float se = 0.0f;
    if (tid < 512) {
        int pixin = (blk & 127) * 512 + tid;    // 0 .. 65535 within batch
        float qy = (float)(pixin >> 8);
        float qx = (float)(pixin & (WW - 1));
        float minr2 = 1e30f;
        #pragma unroll 8
        for (int s = 0; s < NN; ++s) {
            float qpy = qy - p0y[s];
            float qpx = qx - p0x[s];
            float t = (qpy * sdy[s] + qpx * sdx[s]) * sidd[s];
            t = fminf(fmaxf(t, 0.0f), 1.0f);
            float ry = qpy - t * sdy[s];
            float rx = qpx - t * sdx[s];
            minr2 = fminf(minr2, ry * ry + rx * rx);
        }
        float dist = fminf(sqrtf(minr2 + 1e-12f), 15.0f);
        float e = pred[(myBatch << 16) + pixin] - dist;
        se = e * e;
    }
    for (int off = 32; off > 0; off >>= 1) se += __shfl_down(se, off);
    __shared__ float red[16];
    if ((tid & 63) == 0) red[tid >> 6] = se;   // waves 8..15 write 0
    __syncthreads();
    if (tid == 0) {
        float p = 0.0f;
        #pragma unroll
        for (int w = 0; w < 8; ++w) p += red[w];
        st_f(&partials[blk], p);
        asm volatile("s_waitcnt vmcnt(0)" ::: "memory");   // partial before flag
        st_i(&r_flags[blk], MAGIC_R);
    }

    // ========== Phase 4: finalize + flag reset (block 0) ======================
    if (blk == 0 && tid < 64) {
        for (int it = 0; it < SPIN_R; ++it) {
            bool ok = (ld_i(&r_flags[tid*4+0]) == MAGIC_R) &&
                      (ld_i(&r_flags[tid*4+1]) == MAGIC_R) &&
                      (ld_i(&r_flags[tid*4+2]) == MAGIC_R) &&
                      (ld_i(&r_flags[tid*4+3]) == MAGIC_R);
            if (__all(ok)) break;
            __builtin_amdgcn_s_sleep(8);
        }
        float s = 0.0f;
        #pragma unroll
        for (int k = 0; k < 4; ++k)   // fixed order -> deterministic
            s += ld_f(&partials[tid + (k << 6)]);
        for (int off = 32; off > 0; off >>= 1) s += __shfl_down(s, off);
        if (tid == 0) out[0] = s * (1.0f / (float)(NB * HH * WW));
        // reset flags (relaxed MALL stores; everyone is past their last read)
        #pragma unroll
        for (int k = 0; k < 4; ++k) { st_i(&g_flags[tid*4+k], 0); st_i(&r_flags[tid*4+k], 0); }
        if (tid < 16) st_i(&e_rep[tid * 64], 0);
        if (tid < NB) st_i(&xcc_pub[tid], 0);
    }
}

// ---------------- fallback (ws too small): 2-kernel path ---------------------
__device__ __forceinline__ void sample_grad_direct(const float* __restrict__ f,
                                                   float y, float x,
                                                   float& by, float& bx) {
    float yc = fminf(fmaxf(y, 0.0f), 254.999f);
    float xc = fminf(fmaxf(x, 0.0f), 254.999f);
    int r0 = (int)yc, c0 = (int)xc;
    int r1 = r0 + 1, c1 = c0 + 1;
    float wy = yc - (float)r0, wx = xc - (float)c0;
    int rm = max(r0 - 1, 0), rp = min(r1 + 1, HH - 1);
    int cm = max(c0 - 1, 0), cp = min(c1 + 1, WW - 1);
    float sy0 = (r0 == 0) ? 1.0f : 0.5f;
    float sy1 = (r1 == HH - 1) ? 1.0f : 0.5f;
    float sx0 = (c0 == 0) ? 1.0f : 0.5f;
    float sx1 = (c1 == WW - 1) ? 1.0f : 0.5f;
    const float* fr0 = f + (r0 << 8);
    const float* fr1 = f + (r1 << 8);
    const float* frm = f + (rm << 8);
    const float* frp = f + (rp << 8);
    float f00 = fr0[c0], f01 = fr0[c1];
    float f10 = fr1[c0], f11 = fr1[c1];
    float f0m = fr0[cm], f0p = fr0[cp];
    float f1m = fr1[cm], f1p = fr1[cp];
    float fm0 = frm[c0], fm1 = frm[c1];
    float fp0 = frp[c0], fp1 = frp[c1];
    float gy00 = sy0 * (f10 - fm0), gy01 = sy0 * (f11 - fm1);
    float gy10 = sy1 * (fp0 - f00), gy11 = sy1 * (fp1 - f01);
    float gx00 = sx0 * (f01 - f0m), gx01 = sx1 * (f0p - f00);
    float gx10 = sx0 * (f11 - f1m), gx11 = sx1 * (f1p - f10);
    float u = 1.0f - wy, v = 1.0f - wx;
    by = gy00 * u * v + gy01 * u * wx + gy10 * wy * v + gy11 * wy * wx;
    bx = gx00 * u * v + gx01 * u * wx + gx10 * wy * v + gx11 * wy * wx;
}

__global__ __launch_bounds__(64, 1) void evolve_direct_kernel(
        const float* __restrict__ pred,
        const float* __restrict__ nodes_in,
        float* __restrict__ nodes_out,
        int* __restrict__ counter) {
    const int b = blockIdx.x;
    const int l = threadIdx.x;
    if (b == 0 && l == 0)
        __hip_atomic_store(counter, 0, __ATOMIC_RELAXED, __HIP_MEMORY_SCOPE_AGENT);
    const float* f = pred + b * HH * WW;
    const int pl = (l + 63) & 63;
    const int nl = (l + 1) & 63;
    float4 nd = ((const float4*)nodes_in)[b * 64 + l];
    float y0n = nd.x, x0n = nd.y, y1n = nd.z, x1n = nd.w;
    for (int s = 0; s < NSTEPS_K; ++s) {
        float by0, bx0, by1, bx1;
        sample_grad_direct(f, y0n, x0n, by0, bx0);
        sample_grad_direct(f, y1n, x1n, by1, bx1);
        float pya = __shfl(y0n, pl), pxa = __shfl(x0n, pl);
        float pyb = __shfl(y1n, pl), pxb = __shfl(x1n, pl);
        float nya = __shfl(y0n, nl), nxa = __shfl(x0n, nl);
        float nyb = __shfl(y1n, nl), nxb = __shfl(x1n, nl);
        float d2ya = (y1n + pyb) - 2.0f * y0n;
        float d2xa = (x1n + pxb) - 2.0f * x0n;
        float d2yb = (nya + y0n) - 2.0f * y1n;
        float d2xb = (nxa + x0n) - 2.0f * x1n;
        float d2pyb = (y0n + pya) - 2.0f * pyb;
        float d2pxb = (x0n + pxa) - 2.0f * pxb;
        float d2nya = (nyb + y1n) - 2.0f * nya;
        float d2nxa = (nxb + x1n) - 2.0f * nxa;
        float d4ya = (d2yb + d2pyb) - 2.0f * d2ya;
        float d4xa = (d2xb + d2pxb) - 2.0f * d2xa;
        float d4yb = (d2nya + d2ya) - 2.0f * d2yb;
        float d4xb = (d2nxa + d2xa) - 2.0f * d2xb;
        y0n = y0n + 0.1f * ((0.01f * d2ya - 0.01f * d4ya) + (-10.0f * by0));
        x0n = x0n + 0.1f * ((0.01f * d2xa - 0.01f * d4xa) + (-10.0f * bx0));
        y1n = y1n + 0.1f * ((0.01f * d2yb - 0.01f * d4yb) + (-10.0f * by1));
        x1n = x1n + 0.1f * ((0.01f * d2xb - 0.01f * d4xb) + (-10.0f * bx1));
        y0n = fminf(fmaxf(y0n, 0.0f), 255.0f);
        x0n = fminf(fmaxf(x0n, 0.0f), 255.0f);
        y1n = fminf(fmaxf(y1n, 0.0f), 255.0f);
        x1n = fminf(fmaxf(x1n, 0.0f), 255.0f);
    }
    float4 o4; o4.x = y0n; o4.y = x0n; o4.z = y1n; o4.w = x1n;
    ((float4*)nodes_out)[b * 64 + l] = o4;
}

#define RBLK ((HH * WW) / 256)
#define NPART (NB * RBLK)

__global__ void render_kernel(const float* __restrict__ pred,
                              const float* __restrict__ nodes,
                              float* __restrict__ partials,
                              int* __restrict__ counter,
                              float* __restrict__ out) {
    const int b = blockIdx.y;
    const int chunk = blockIdx.x;
    const int tid = threadIdx.x;
    __shared__ float p0y[NN], p0x[NN], sdy[NN], sdx[NN], sidd[NN];
    if (tid < NN) {
        float ay = nodes[(b * NN + tid) * 2 + 0];
        float ax = nodes[(b * NN + tid) * 2 + 1];
        int j = (tid + 1) & (NN - 1);
        float cy = nodes[(b * NN + j) * 2 + 0];
        float cx = nodes[(b * NN + j) * 2 + 1];
        float ddy = cy - ay, ddx = cx - ax;
        p0y[tid] = ay; p0x[tid] = ax;
        sdy[tid] = ddy; sdx[tid] = ddx;
        sidd[tid] = 1.0f / (ddy * ddy + ddx * ddx + 1e-8f);
    }
    __syncthreads();
    const int pix = chunk * 256 + tid;
    const float qy = (float)(pix >> 8);
    const float qx = (float)(pix & (WW - 1));
    float minr2 = 1e30f;
#pragma unroll 8
    for (int s = 0; s < NN; ++s) {
        float qpy = qy - p0y[s];
        float qpx = qx - p0x[s];
        float t = (qpy * sdy[s] + qpx * sdx[s]) * sidd[s];
        t = fminf(fmaxf(t, 0.0f), 1.0f);
        float ry = qpy - t * sdy[s];
        float rx = qpx - t * sdx[s];
        minr2 = fminf(minr2, ry * ry + rx * rx);
    }
    float dist = fminf(sqrtf(minr2 + 1e-12f), 15.0f);
    float e = pred[b * HH * WW + pix] - dist;
    float se = e * e;
    for (int off = 32; off > 0; off >>= 1) se += __shfl_down(se, off);
    __shared__ float red[4];
    if ((tid & 63) == 0) red[tid >> 6] = se;
    __syncthreads();
    __shared__ int lastBlk;
    if (tid == 0) {
        float p = (red[0] + red[1]) + (red[2] + red[3]);
        __hip_atomic_store(&partials[b * RBLK + chunk], p, __ATOMIC_RELEASE, __HIP_MEMORY_SCOPE_AGENT);
        int t = __hip_atomic_fetch_add(counter, 1, __ATOMIC_ACQ_REL, __HIP_MEMORY_SCOPE_AGENT);
        lastBlk = (t == NPART - 1);
    }
    __syncthreads();
    if (lastBlk) {
        float v = __hip_atomic_load(&partials[tid], __ATOMIC_RELAXED, __HIP_MEMORY_SCOPE_AGENT)
                + __hip_atomic_load(&partials[tid + 256], __ATOMIC_RELAXED, __HIP_MEMORY_SCOPE_AGENT);
        for (int off = 32; off > 0; off >>= 1) v += __shfl_down(v, off);
        __shared__ float red2[4];
        if ((tid & 63) == 0) red2[tid >> 6] = v;
        __syncthreads();
        if (tid == 0)
            out[0] = ((red2[0] + red2[1]) + (red2[2] + red2[3])) * (1.0f / (float)(NB * HH * WW));
    }
}

extern "C" void kernel_launch(void* const* d_in, const int* in_sizes, int n_in,
                              void* d_out, int out_size, void* d_ws, size_t ws_size,
                              hipStream_t stream) {
    const float* pred = (const float*)d_in[0];    // (B,1,H,W) f32
    const float* nodes = (const float*)d_in[1];   // (B,N,2) f32
    float* ws = (float*)d_ws;

    if (ws_size >= WS_NEEDED_BYTES) {
        fused4_kernel<<<dim3(NBLK), dim3(1024), 0, stream>>>(pred, nodes, ws, (float*)d_out);
    } else {
        float* partials = ws;                  // 512 f
        float* fnodes = ws + 512;              // 512 f
        int* counter = (int*)(ws + 1024);
        evolve_direct_kernel<<<dim3(NB), dim3(64), 0, stream>>>(pred, nodes, fnodes, counter);
        render_kernel<<<dim3(RBLK, NB), dim3(256), 0, stream>>>(pred, fnodes, partials,
                                                                counter, (float*)d_out);
    }
}